// Round 9
// baseline (248.414 us; speedup 1.0000x reference)
//
#include <hip/hip_runtime.h>

// ReActNet BasicBlock forward: out = BN(binary_conv3x3(sign(x), scale*sign(w))) + x
//
// i8 MFMA implicit-GEMM, LDS-staged stencil (r8 + occupancy + column-swizzle):
//   sign(x) -> padded NHWC i8 tensor S[n][58][58][128], XOR-swizzled in 16B
//              slots with key = (col+1)&7 (COLUMN-based; W=56 ≡ 0 mod 8 makes
//              residues continuous across row wraps -> no bank imbalance).
//   sign(w) -> A-fragment-layout blob wfrag[otile][tap][ks][lane] (v4i)
//   Block = 256 thr = 4 waves = 4 o-tiles; each wave: 32 o x 128 px as 4
//   independent MFMA chains. S window (264 px = 33 KB) staged once per block.
//   launch_bounds(256,4): 4 blocks/CU (135 KB LDS) for deeper inter-block
//   pipelining (r8 measured 30% occupancy at 3 blocks/CU, latency-bound).

#define N_   64
#define C_   128
#define H_   56
#define W_   56
#define HW_  (H_*W_)       // 3136
#define PH_  (H_+2)        // 58
#define PW_  (W_+2)        // 58
#define PHW_ (PH_*PW_)     // 3364
#define NPIX (N_*HW_)      // 200704
#define NPAD (N_*PHW_)     // 215296
#define SBYTES ((size_t)NPAD * 128)   // 27,557,888
#define SPIX 264           // staged pixels per block (33792 B LDS)

typedef int v4i  __attribute__((ext_vector_type(4)));
typedef int v16i __attribute__((ext_vector_type(16)));

__device__ __forceinline__ void glds16(const char* g, char* l) {
    __builtin_amdgcn_global_load_lds(
        (const __attribute__((address_space(1))) void*)g,
        (__attribute__((address_space(3))) void*)l, 16, 0, 0);
}

__device__ __forceinline__ unsigned sign_byte(unsigned u) {
    // {+1, 0 (exact zero incl -0.0), 0xFF}
    return ((u << 1) == 0u) ? 0u : ((u >> 31) ? 0xFFu : 1u);
}

// ---------------------------------------------------------------------------
// Kernel 1: fused weight prep. One 64-thread block per output channel o.
// ---------------------------------------------------------------------------
__global__ void prep_w_kernel(const float* __restrict__ w,
                              const float* __restrict__ gamma,
                              const float* __restrict__ beta,
                              const float* __restrict__ bn_mean,
                              const float* __restrict__ bn_var,
                              v4i* __restrict__ wfrag,
                              float2* __restrict__ AB) {
    const int o = blockIdx.x;
    const int lane = threadIdx.x;          // 0..63
    const float* wo = w + o * 1152;

    float s = 0.f;
    #pragma unroll
    for (int k = 0; k < 18; k++) s += fabsf(wo[k * 64 + lane]);
    #pragma unroll
    for (int off = 32; off > 0; off >>= 1) s += __shfl_down(s, off);

    // fragments: 72 total; lane builds f=lane, and f=64+lane for lane<8
    #pragma unroll
    for (int rep = 0; rep < 2; rep++) {
        int f = rep * 64 + lane;
        if (f < 72) {
            int t = f >> 3, ks = (f >> 1) & 3, lh = f & 1;
            int cbase = ks * 32 + lh * 16;
            unsigned d[4];
            #pragma unroll
            for (int i = 0; i < 4; i++) {
                unsigned wd = 0;
                #pragma unroll
                for (int j = 0; j < 4; j++) {
                    unsigned u = __float_as_uint(wo[(cbase + i * 4 + j) * 9 + t]);
                    wd |= sign_byte(u) << (8 * j);
                }
                d[i] = wd;
            }
            v4i v; v.x=(int)d[0]; v.y=(int)d[1]; v.z=(int)d[2]; v.w=(int)d[3];
            wfrag[(((o >> 5) * 9 + t) * 4 + ks) * 64 + (lh << 5) + (o & 31)] = v;
        }
    }
    if (lane == 0) {
        float scale = s * (1.0f / 1152.0f);
        float inv = gamma[o] * rsqrtf(bn_var[o] + 1e-5f);
        float2 ab; ab.x = scale * inv; ab.y = beta[o] - bn_mean[o] * inv;
        AB[o] = ab;
    }
}

// ---------------------------------------------------------------------------
// Kernel 2: binarize x into padded, slot-swizzled NHWC i8.
//   Swizzle key m = (col+1)&7 (column-based). Border blocks zero the frame
//   (zeros are swizzle-invariant).
// ---------------------------------------------------------------------------
__global__ __launch_bounds__(256) void pack_s_kernel(
        const float* __restrict__ x, char* __restrict__ S) {
    const int tid = threadIdx.x;
    const int pixl = tid & 63, q = tid >> 6;      // q = channel quarter
    const int b = blockIdx.x;

    if (b >= NPIX / 64) {                          // border: 228 blocks
        int bt = (b - NPIX / 64) * 64 + pixl;      // 0..14591
        int n = bt / 228, e = bt - n * 228;
        int ph, pw;
        if (e < 58)       { ph = 0;  pw = e; }
        else if (e < 116) { ph = 57; pw = e - 58; }
        else { int i = e - 116; ph = 1 + (i >> 1); pw = (i & 1) ? 57 : 0; }
        v4i z = {};
        char* dst = S + (size_t)((n * PH_ + ph) * PW_ + pw) * 128 + q * 32;
        ((v4i*)dst)[0] = z;
        ((v4i*)dst)[1] = z;
        return;
    }

    const int g = b * 64 + pixl;                   // 0..NPIX-1
    const int n = g / HW_;
    const int p = g - n * HW_;
    const int row = p / W_, col = p - row * W_;

    const float* xp = x + ((size_t)n * C_ + q * 32) * HW_ + p;
    unsigned w[8];
    #pragma unroll
    for (int i = 0; i < 8; i++) {
        unsigned wd = 0;
        #pragma unroll
        for (int j = 0; j < 4; j++) {
            unsigned u = __float_as_uint(xp[(i * 4 + j) * HW_]);
            wd |= sign_byte(u) << (8 * j);
        }
        w[i] = wd;
    }
    const int P = (n * PH_ + row + 1) * PW_ + col + 1;   // padded pixel index
    const int m = (col + 1) & 7;                          // COLUMN swizzle key
    char* base = S + (size_t)P * 128;
    v4i t0; t0.x=(int)w[0]; t0.y=(int)w[1]; t0.z=(int)w[2]; t0.w=(int)w[3];
    v4i t1; t1.x=(int)w[4]; t1.y=(int)w[5]; t1.z=(int)w[6]; t1.w=(int)w[7];
    *(v4i*)(base + (((2 * q)     ^ m) << 4)) = t0;
    *(v4i*)(base + (((2 * q + 1) ^ m) << 4)) = t1;
}

// ---------------------------------------------------------------------------
// Kernel 3: i8 MFMA conv + BN + residual, LDS-staged.
//   grid = 1600 = 64 images * 25 pixel-blocks (128 px; tail 64 px masked).
//   XCD-bijective swizzle (1600 % 8 == 0).
//   ds_read addr: (lpt<<7) ^ (key<<4) ^ (lhi<<4) ^ (ks<<5),
//   key = (c1 + dw)&7 — matches pack's column key for the tap's column;
//   vertical taps share the column, border taps are all-zero (key-free).
// ---------------------------------------------------------------------------
__global__ __launch_bounds__(256, 4) void bconv_mfma_kernel(
        const char* __restrict__ S,
        const v4i* __restrict__ wfrag,
        const float2* __restrict__ AB,
        const float* __restrict__ x,
        float* __restrict__ out) {
    __shared__ char Sl[SPIX * 128];

    const int tid = threadIdx.x;
    const int lane = tid & 63;
    const int wid = tid >> 6;                  // wave = o-tile
    const int l31 = lane & 31, lhi = lane >> 5;

    const int b0 = blockIdx.x;
    const int bid = (b0 & 7) * 200 + (b0 >> 3);
    const int n = bid / 25;
    const int pb = bid - n * 25;
    const int p0 = pb * 128;

    const int r0 = p0 / W_, c0 = p0 - r0 * W_;
    const int P0 = (n * PH_ + r0 + 1) * PW_ + (c0 + 1);
    const int qs8 = (P0 - PW_ - 1) & ~7;       // staging start (8-aligned)

    // Stage S[qs8 .. qs8+SPIX) -> LDS, linear copy (33 wave-issues of 1 KiB).
    // Last-image blocks over-read <=10.3 KiB past S end -> lands in wfrag+AB
    // (mapped; those LDS pixels are never consumed).
    {
        const char* gsrc = S + (size_t)qs8 * 128 + lane * 16;
        #pragma unroll
        for (int i = 0; i < 9; i++) {
            int seg = i * 4 + wid;             // wave-uniform predicate
            if (seg < (SPIX * 128) / 1024)
                glds16(gsrc + seg * 1024, &Sl[seg * 1024]);
        }
    }

    // Per-chain geometry (overlaps with staging loads).
    int lpx[4]; int kb[4]; bool val[4]; int pix[4];
    #pragma unroll
    for (int ch = 0; ch < 4; ch++) {
        int p = p0 + ch * 32 + l31;
        val[ch] = (p < HW_);
        if (!val[ch]) p = HW_ - 1;
        pix[ch] = p;
        int r = p / W_, c = p - r * W_;
        lpx[ch] = (n * PH_ + r + 1) * PW_ + (c + 1) - qs8;
        kb[ch]  = c + 1;                       // column key base
    }
    const int kc1 = lhi << 4;

    __syncthreads();

    v16i acc[4] = {};
    const v4i* wbase = wfrag + (size_t)wid * (9 * 4 * 64) + lane;

    // A-fragment double-buffer (A is the only global-latency chain left).
    v4i Acur[4], Anxt[4];
    #pragma unroll
    for (int ks = 0; ks < 4; ks++) Acur[ks] = wbase[ks * 64];

    #pragma unroll
    for (int t = 0; t < 9; t++) {
        if (t < 8) {
            #pragma unroll
            for (int ks = 0; ks < 4; ks++)
                Anxt[ks] = wbase[((t + 1) * 4 + ks) * 64];
        }
        const int tp = (t / 3 - 1) * PW_ + (t % 3 - 1);
        const int dw = t % 3 - 1;
        int A0[4];
        #pragma unroll
        for (int ch = 0; ch < 4; ch++) {
            int lpt = lpx[ch] + tp;
            int key = (kb[ch] + dw) & 7;
            A0[ch] = (lpt << 7) ^ (key << 4) ^ kc1;
        }
        #pragma unroll
        for (int ks = 0; ks < 4; ks++) {
            #pragma unroll
            for (int ch = 0; ch < 4; ch++) {
                v4i bb = *(const v4i*)(&Sl[A0[ch] ^ (ks << 5)]);
                acc[ch] = __builtin_amdgcn_mfma_i32_32x32x32_i8(Acur[ks], bb,
                                                                acc[ch], 0, 0, 0);
            }
        }
        if (t < 8) {
            #pragma unroll
            for (int ks = 0; ks < 4; ks++) Acur[ks] = Anxt[ks];
        }
    }

    // Epilogue: out = A*dot + B + x
    const int obase = wid * 32 + 4 * lhi;
    #pragma unroll
    for (int ch = 0; ch < 4; ch++) {
        if (!val[ch]) continue;
        unsigned base = (unsigned)n * (unsigned)(C_ * HW_) + (unsigned)pix[ch];
        #pragma unroll
        for (int r = 0; r < 16; r++) {
            int o = obase + (r & 3) + 8 * (r >> 2);
            float2 ab = AB[o];
            unsigned idx = base + (unsigned)o * (unsigned)HW_;
            out[idx] = fmaf(ab.x, (float)acc[ch][r], ab.y) + x[idx];
        }
    }
}

// ---------------------------------------------------------------------------
extern "C" void kernel_launch(void* const* d_in, const int* in_sizes, int n_in,
                              void* d_out, int out_size, void* d_ws, size_t ws_size,
                              hipStream_t stream) {
    const float* x      = (const float*)d_in[0];
    const float* weight = (const float*)d_in[1];
    const float* gamma  = (const float*)d_in[2];
    const float* beta   = (const float*)d_in[3];
    const float* bnmean = (const float*)d_in[4];
    const float* bnvar  = (const float*)d_in[5];
    float* out = (float*)d_out;

    // Layout (r8-proven): S = NPAD*128 = 27,557,888 B, then wfrag, AB.
    char* ws = (char*)d_ws;
    char*   S     = ws;                                   // SBYTES
    v4i*    wfrag = (v4i*)(ws + SBYTES);                  // 147456 B
    float2* AB    = (float2*)(ws + SBYTES + 147456);      // 1024 B

    prep_w_kernel<<<128, 64, 0, stream>>>(weight, gamma, beta, bnmean, bnvar,
                                          wfrag, AB);
    pack_s_kernel<<<NPIX / 64 + 228, 256, 0, stream>>>(x, S);
    bconv_mfma_kernel<<<1600, 256, 0, stream>>>(S, wfrag, AB, x, out);
}